// Round 1
// baseline (1034.388 us; speedup 1.0000x reference)
//
#include <hip/hip_runtime.h>
#include <math.h>

#define TTOK 8192
#define DDIM 1024
#define HDIM 4096
#define NEXP 8
#define NASSIGN (TTOK * 2)

typedef float f32x4 __attribute__((ext_vector_type(4)));
typedef short s16x8 __attribute__((ext_vector_type(8)));

__device__ __forceinline__ unsigned short f2bf(float f) {
  union { float f; unsigned int u; } v; v.f = f;
  unsigned int u = v.u;
  u += 0x7FFFu + ((u >> 16) & 1u);   // RNE
  return (unsigned short)(u >> 16);
}

// gelu_tanh(x) = 0.5x(1+tanh(u)) = x * sigmoid(2u),  u = sqrt(2/pi)(x+0.044715x^3)
__device__ __forceinline__ float gelu_fast(float x) {
  float u = 0.7978845608028654f * x * (1.0f + 0.044715f * x * x);
  return x / (1.0f + __expf(-2.0f * u));
}

// ---- fp32 -> bf16 conversion of BOTH weight tensors, one launch, 2 float4/thread ----
__global__ void cvt_bf16_k(const float* __restrict__ w1, unsigned short* __restrict__ w1b,
                           const float* __restrict__ w2, unsigned short* __restrict__ w2b,
                           int n8) {  // n8 = float8-chunks per tensor
  int i = blockIdx.x * blockDim.x + threadIdx.x;
  const float* src; unsigned short* dst;
  if (i < n8) { src = w1; dst = w1b; } else { src = w2; dst = w2b; i -= n8; }
#pragma unroll
  for (int c = 0; c < 2; ++c) {
    float4 v = ((const float4*)src)[i * 2 + c];
    ushort4 o;
    o.x = f2bf(v.x); o.y = f2bf(v.y); o.z = f2bf(v.z); o.w = f2bf(v.w);
    ((ushort4*)dst)[i * 2 + c] = o;
  }
}

// ---- router: logits = (x + se[sidx]) @ rw^T + rb ; top-2 + softmax ----
__global__ void router_k(const float* __restrict__ x, const float* __restrict__ se,
                         const int* __restrict__ sidx, const float* __restrict__ rw,
                         const float* __restrict__ rb,
                         int* __restrict__ e0, int* __restrict__ e1,
                         float* __restrict__ w0, float* __restrict__ w1,
                         int* __restrict__ counts) {
  int t = blockIdx.x * 4 + (threadIdx.x >> 6);
  int lane = threadIdx.x & 63;
  const float4* xp = (const float4*)(x + (size_t)t * DDIM) + lane * 4;
  const float4* sp = (const float4*)(se + (size_t)sidx[0] * DDIM) + lane * 4;
  float xs[16];
#pragma unroll
  for (int c = 0; c < 4; ++c) {
    float4 a = xp[c], b = sp[c];
    xs[c * 4 + 0] = a.x + b.x; xs[c * 4 + 1] = a.y + b.y;
    xs[c * 4 + 2] = a.z + b.z; xs[c * 4 + 3] = a.w + b.w;
  }
  double acc[NEXP];
#pragma unroll
  for (int e = 0; e < NEXP; ++e) acc[e] = 0.0;
#pragma unroll
  for (int e = 0; e < NEXP; ++e) {
    const float4* wp = (const float4*)(rw + (size_t)e * DDIM) + lane * 4;
#pragma unroll
    for (int c = 0; c < 4; ++c) {
      float4 wv = wp[c];
      acc[e] += (double)xs[c * 4 + 0] * wv.x + (double)xs[c * 4 + 1] * wv.y +
                (double)xs[c * 4 + 2] * wv.z + (double)xs[c * 4 + 3] * wv.w;
    }
  }
#pragma unroll
  for (int e = 0; e < NEXP; ++e) {
#pragma unroll
    for (int m = 32; m >= 1; m >>= 1) acc[e] += __shfl_xor(acc[e], m, 64);
  }
  if (lane == 0) {
    float lg[NEXP];
    for (int e = 0; e < NEXP; ++e) lg[e] = (float)acc[e] + rb[e];
    int i0 = 0; float l0 = lg[0];
    for (int e = 1; e < NEXP; ++e) if (lg[e] > l0) { l0 = lg[e]; i0 = e; }
    int i1 = -1; float l1 = -1e30f;
    for (int e = 0; e < NEXP; ++e) if (e != i0 && lg[e] > l1) { l1 = lg[e]; i1 = e; }
    float z = expf(l1 - l0);
    float p0 = 1.0f / (1.0f + z);
    e0[t] = i0; e1[t] = i1; w0[t] = p0; w1[t] = 1.0f - p0;
    atomicAdd(&counts[i0], 1);
    atomicAdd(&counts[i1], 1);
  }
}

// prefix-scan + build m-tile table (256-row tiles now: <=72 entries of {m0, row1, e, 0})
__global__ void scan_k(const int* __restrict__ counts, int* __restrict__ offsets,
                       int* __restrict__ cursors, int4* __restrict__ tileT,
                       int* __restrict__ ntiles) {
  if (threadIdx.x == 0 && blockIdx.x == 0) {
    int s = 0;
    for (int e = 0; e < NEXP; ++e) { offsets[e] = s; cursors[e] = s; s += counts[e]; }
    offsets[NEXP] = s;
    int nt = 0;
    for (int e = 0; e < NEXP; ++e)
      for (int m0 = offsets[e]; m0 < offsets[e + 1]; m0 += 256)
        tileT[nt++] = make_int4(m0, offsets[e + 1], e, 0);
    ntiles[0] = nt;
  }
}

__global__ void scatter_k(const int* __restrict__ e0, const int* __restrict__ e1,
                          const float* __restrict__ w0, const float* __restrict__ w1,
                          int* __restrict__ cursors, int* __restrict__ buckets,
                          float* __restrict__ wts, int* __restrict__ s0,
                          int* __restrict__ s1) {
  int t = blockIdx.x * blockDim.x + threadIdx.x;
  if (t >= TTOK) return;
  int a = e0[t];
  int p = atomicAdd(&cursors[a], 1);
  buckets[p] = t; wts[p] = w0[t]; s0[t] = p;
  a = e1[t];
  p = atomicAdd(&cursors[a], 1);
  buckets[p] = t; wts[p] = w1[t]; s1[t] = p;
}

// gather token rows (raw x) into compacted bf16 A matrix
__global__ void gather_k(const float* __restrict__ x, const int* __restrict__ buckets,
                         unsigned short* __restrict__ Xg) {
  int r = blockIdx.x;
  int t = buckets[r];
  int i = threadIdx.x;
  float4 v = ((const float4*)(x + (size_t)t * DDIM))[i];
  ushort4 o;
  o.x = f2bf(v.x); o.y = f2bf(v.y); o.z = f2bf(v.z); o.w = f2bf(v.w);
  ((ushort4*)(Xg + (size_t)r * DDIM))[i] = o;
}

// =====================================================================
// persistent grouped NT GEMM, 256x256 tile, BK=64, 8-phase schedule
// (m201 template: counted vmcnt(4), never 0 in main loop; setprio around
// MFMA clusters; XOR-swizzled LDS via pre-swizzled global source).
// 512 threads = 8 waves (2M x 4N), per-wave 128x64 output, acc[8][4].
// LDS 128 KiB dynamic: A[2][256x64] + B[2][256x64] bf16, double-buffered.
//
// Iteration i computes K-tiles (2i)->slot0 in phases 1-4, (2i+1)->slot1 in
// phases 5-8. Stage windows (region freed by trailing barrier of the last
// phase that reads it):
//   ph1: A(2i+1)h0   ph2: A(2i+1)h1    [slot1 A freed after prev ph8]
//   ph3: B(2i+2)h0   ph4: B(2i+2)h1    [slot0 B read only in ph1]
//   ph5: A(2i+2)h0   ph6: A(2i+2)h1    [slot0 A freed after ph4]
//   ph7: B(2i+3)h0   ph8: B(2i+3)h1    [slot1 B read only in ph5]
// vmcnt(4) before barriers of ph4/ph8 guarantees the next K-tile's A+B
// landed in every wave (cross-wave via the barrier), leaving 4 loads in
// flight. Tail K-tiles >= NKT clamp the source k-offset (slots already
// free; counts stay uniform so vmcnt semantics hold).
// =====================================================================

#define ASP1(p) (const __attribute__((address_space(1))) void*)(p)
#define ASP3(p) (__attribute__((address_space(3))) void*)(p)

#define STAGE_A(KT, H) do {                                                   \
    int kk_ = (KT); if (kk_ >= NKT) kk_ = NKT - 1;                            \
    const int k0_ = kk_ * 64;                                                 \
    unsigned short* d_ = (((KT) & 1) ? LA1 : LA0) + ((H) * 128 + w * 8) * 64; \
    __builtin_amdgcn_global_load_lds(ASP1(aptr[(H) * 2 + 0] + k0_), ASP3(d_), 16, 0, 0);        \
    __builtin_amdgcn_global_load_lds(ASP1(aptr[(H) * 2 + 1] + k0_), ASP3(d_ + 4096), 16, 0, 0); \
  } while (0)

#define STAGE_B(KT, H) do {                                                   \
    int kk_ = (KT); if (kk_ >= NKT) kk_ = NKT - 1;                            \
    const int k0_ = kk_ * 64;                                                 \
    unsigned short* d_ = (((KT) & 1) ? LB1 : LB0) + ((H) * 128 + w * 8) * 64; \
    __builtin_amdgcn_global_load_lds(ASP1(bptr[(H) * 2 + 0] + k0_), ASP3(d_), 16, 0, 0);        \
    __builtin_amdgcn_global_load_lds(ASP1(bptr[(H) * 2 + 1] + k0_), ASP3(d_ + 4096), 16, 0, 0); \
  } while (0)

// one phase: ds_read subtile || stage issue -> barrier -> lgkm(0) -> 16 MFMA
#define PH(SL, QD, RB, STG) do {                                              \
    if (RB) {                                                                 \
      _Pragma("unroll") for (int nj_ = 0; nj_ < 4; ++nj_)                     \
      _Pragma("unroll") for (int ks_ = 0; ks_ < 2; ++ks_)                     \
        bfrag[nj_][ks_] = *(const s16x8*)(((SL) ? LB1 : LB0) +                \
            (wn * 64 + nj_ * 16 + c16) * 64 + (((ks_ * 4 + q) ^ cx) * 8));    \
    }                                                                         \
    s16x8 afr_[2][2];                                                         \
    _Pragma("unroll") for (int m2_ = 0; m2_ < 2; ++m2_)                       \
    _Pragma("unroll") for (int ks_ = 0; ks_ < 2; ++ks_)                       \
      afr_[m2_][ks_] = *(const s16x8*)(((SL) ? LA1 : LA0) +                   \
          (wm * 128 + ((QD) * 2 + m2_) * 16 + c16) * 64 +                     \
          (((ks_ * 4 + q) ^ cx) * 8));                                        \
    STG;                                                                      \
    asm volatile("s_barrier" ::: "memory");                                   \
    asm volatile("s_waitcnt lgkmcnt(0)" ::: "memory");                        \
    __builtin_amdgcn_sched_barrier(0);                                        \
    __builtin_amdgcn_s_setprio(1);                                            \
    _Pragma("unroll") for (int m2_ = 0; m2_ < 2; ++m2_)                       \
    _Pragma("unroll") for (int nj_ = 0; nj_ < 4; ++nj_)                       \
    _Pragma("unroll") for (int ks_ = 0; ks_ < 2; ++ks_)                       \
      acc[(QD) * 2 + m2_][nj_] = __builtin_amdgcn_mfma_f32_16x16x32_bf16(     \
          afr_[m2_][ks_], bfrag[nj_][ks_], acc[(QD) * 2 + m2_][nj_], 0, 0, 0);\
    __builtin_amdgcn_s_setprio(0);                                            \
  } while (0)

#define BARS asm volatile("s_barrier" ::: "memory")
#define VM4  asm volatile("s_waitcnt vmcnt(4)" ::: "memory")

template <int KD, int ND, int EPI>
__global__ __launch_bounds__(512, 2) void moe_gemm8_k(
    const unsigned short* __restrict__ A,   // compacted slots x KD (bf16)
    const unsigned short* __restrict__ W,   // NEXP x ND x KD (bf16)
    const float* __restrict__ bias,         // NEXP x ND
    const int4* __restrict__ tileT, const int* __restrict__ ntiles,
    unsigned short* __restrict__ Hout, float* __restrict__ Yout) {
  constexpr int NTN = ND / 256;
  constexpr int NKT = KD / 64;
  extern __shared__ unsigned short lds[];
  unsigned short* const LA0 = lds;                 // A slot0: 256x64
  unsigned short* const LA1 = lds + 16384;         // A slot1
  unsigned short* const LB0 = lds + 32768;         // B slot0
  unsigned short* const LB1 = lds + 49152;         // B slot1

  const int tid = threadIdx.x;
  const int lane = tid & 63;
  const int w = tid >> 6;        // wave 0..7
  const int wm = w >> 2;         // 0..1 (M)
  const int wn = w & 3;          // 0..3 (N)
  const int q = lane >> 4;
  const int c16 = lane & 15;
  const int cx = lane & 7;
  const int l8 = lane >> 3;
  const int swz = cx ^ l8;       // pre-swizzled global chunk

  const int ntm = ntiles[0];
  const int total = ntm * NTN;
  const int xcd = blockIdx.x & 7;
  const int lid = blockIdx.x >> 3;
  const int bstride = gridDim.x >> 3;
  // contiguous idx-chunk per XCD, m-fastest enumeration -> B panel stays in L2
  const int per = (total + 7) >> 3;
  int begin = xcd * per;
  int end = begin + per; if (end > total) end = total;

  for (int idx = begin + lid; idx < end; idx += bstride) {
    const int nb = idx / ntm;
    const int mt = idx - nb * ntm;
    const int4 tl = tileT[mt];
    const int m0 = tl.x, row1 = tl.y, e = tl.z;
    const int n0 = nb * 256;
    const unsigned short* We = W + (size_t)e * ND * KD;

    // staging row base pointers (4 loads each for A and B, 64 rows per load)
    const unsigned short* aptr[4];
    const unsigned short* bptr[4];
#pragma unroll
    for (int i = 0; i < 4; ++i) {
      int ar = m0 + i * 64 + w * 8 + l8;
      if (ar > row1 - 1) ar = row1 - 1;  // clamp: duplicate rows masked at store
      aptr[i] = A + (size_t)ar * KD + swz * 8;
      bptr[i] = We + (size_t)(n0 + i * 64 + w * 8 + l8) * KD + swz * 8;
    }

    f32x4 acc[8][4];
#pragma unroll
    for (int i = 0; i < 8; ++i)
#pragma unroll
      for (int j = 0; j < 4; ++j) acc[i][j] = {0.f, 0.f, 0.f, 0.f};

    s16x8 bfrag[4][2];

    // drain leftover tail-stages/epilogue stores (same-wave WW hazard on LDS)
    asm volatile("s_waitcnt vmcnt(0)" ::: "memory");
    // prologue: A(0), B(0), B(1); A(1) is staged by iter0 ph1-2
    STAGE_A(0, 0); STAGE_A(0, 1);
    STAGE_B(0, 0); STAGE_B(0, 1);
    STAGE_B(1, 0); STAGE_B(1, 1);
    asm volatile("s_waitcnt vmcnt(4)" ::: "memory");  // A(0),B(0) landed
    asm volatile("s_barrier" ::: "memory");

    for (int it = 0; it < NKT / 2; ++it) {
      const int t2 = 2 * it;
      PH(0, 0, 1, STAGE_A(t2 + 1, 0)); BARS;
      PH(0, 1, 0, STAGE_A(t2 + 1, 1)); BARS;
      PH(0, 2, 0, STAGE_B(t2 + 2, 0)); BARS;
      PH(0, 3, 0, STAGE_B(t2 + 2, 1)); VM4; BARS;
      PH(1, 0, 1, STAGE_A(t2 + 2, 0)); BARS;
      PH(1, 1, 0, STAGE_A(t2 + 2, 1)); BARS;
      PH(1, 2, 0, STAGE_B(t2 + 3, 0)); BARS;
      PH(1, 3, 0, STAGE_B(t2 + 3, 1)); VM4; BARS;
    }

    // epilogue: C/D layout col=lane&15, row=(lane>>4)*4+reg  [m89/m91-verified]
    float bj[4];
#pragma unroll
    for (int nj = 0; nj < 4; ++nj)
      bj[nj] = bias[(size_t)e * ND + n0 + wn * 64 + nj * 16 + c16];
#pragma unroll
    for (int mi = 0; mi < 8; ++mi) {
#pragma unroll
      for (int r = 0; r < 4; ++r) {
        const int m = m0 + wm * 128 + mi * 16 + q * 4 + r;
        if (m < row1) {
#pragma unroll
          for (int nj = 0; nj < 4; ++nj) {
            const int n = n0 + wn * 64 + nj * 16 + c16;
            if (EPI == 0)
              Hout[(size_t)m * ND + n] = f2bf(gelu_fast(acc[mi][nj][r] + bj[nj]));
            else
              Yout[(size_t)m * ND + n] = acc[mi][nj][r] + bj[nj];
          }
        }
      }
    }
  }
}

// out[t] = w(s0)*Y[s0[t]] + w(s1)*Y[s1[t]]
__global__ void combine_k(const float* __restrict__ Yr, const int* __restrict__ s0,
                          const int* __restrict__ s1, const float* __restrict__ wts,
                          float* __restrict__ out) {
  int t = blockIdx.x;
  int i = threadIdx.x;
  int a = s0[t], b = s1[t];
  float wa = wts[a], wb = wts[b];
  float4 va = ((const float4*)(Yr + (size_t)a * DDIM))[i];
  float4 vb = ((const float4*)(Yr + (size_t)b * DDIM))[i];
  float4 o;
  o.x = wa * va.x + wb * vb.x;
  o.y = wa * va.y + wb * vb.y;
  o.z = wa * va.z + wb * vb.z;
  o.w = wa * va.w + wb * vb.w;
  ((float4*)(out + (size_t)t * DDIM))[i] = o;
}

extern "C" void kernel_launch(void* const* d_in, const int* in_sizes, int n_in,
                              void* d_out, int out_size, void* d_ws, size_t ws_size,
                              hipStream_t stream) {
  const float* x  = (const float*)d_in[0];
  const float* se = (const float*)d_in[1];
  const float* rw = (const float*)d_in[2];
  const float* rb = (const float*)d_in[3];
  const float* w1 = (const float*)d_in[4];
  const float* b1 = (const float*)d_in[5];
  const float* w2 = (const float*)d_in[6];
  const float* b2 = (const float*)d_in[7];
  const int* sidx = (const int*)d_in[8];
  float* out = (float*)d_out;

  char* ws = (char*)d_ws;
  size_t off = 0;
  unsigned short* w1b = (unsigned short*)(ws + off); off += (size_t)NEXP * HDIM * DDIM * 2;  // 64 MB
  unsigned short* w2b = (unsigned short*)(ws + off); off += (size_t)NEXP * DDIM * HDIM * 2;  // 64 MB
  unsigned short* Xg  = (unsigned short*)(ws + off); off += (size_t)NASSIGN * DDIM * 2;      // 32 MB
  unsigned short* Hb  = (unsigned short*)(ws + off); off += (size_t)NASSIGN * HDIM * 2;      // 128 MB
  float* Yr = (float*)w1b;  // 64 MB, overlays w1b (dead after fc1)
  int*   counts  = (int*)(ws + off); off += 64;
  int*   offsets = (int*)(ws + off); off += 64;
  int*   cursors = (int*)(ws + off); off += 64;
  int*   ntiles  = (int*)(ws + off); off += 64;
  int*   e0  = (int*)(ws + off);   off += (size_t)TTOK * 4;
  int*   e1  = (int*)(ws + off);   off += (size_t)TTOK * 4;
  float* tw0 = (float*)(ws + off); off += (size_t)TTOK * 4;
  float* tw1 = (float*)(ws + off); off += (size_t)TTOK * 4;
  int*   s0  = (int*)(ws + off);   off += (size_t)TTOK * 4;
  int*   s1  = (int*)(ws + off);   off += (size_t)TTOK * 4;
  int*   buckets = (int*)(ws + off); off += (size_t)NASSIGN * 4;
  float* wts = (float*)(ws + off);   off += (size_t)NASSIGN * 4;
  int4*  tileT = (int4*)(ws + off);  off += 256 * 16;

  // 128 KiB dynamic LDS opt-in (host-side attribute, graph-capture safe)
  static int lds_attr_done = 0;
  if (!lds_attr_done) {
    (void)hipFuncSetAttribute((const void*)moe_gemm8_k<DDIM, HDIM, 0>,
                              hipFuncAttributeMaxDynamicSharedMemorySize, 131072);
    (void)hipFuncSetAttribute((const void*)moe_gemm8_k<HDIM, DDIM, 1>,
                              hipFuncAttributeMaxDynamicSharedMemorySize, 131072);
    lds_attr_done = 1;
  }

  hipMemsetAsync(counts, 0, 64, stream);

  const int n8 = NEXP * HDIM * DDIM / 8;
  cvt_bf16_k<<<2 * n8 / 256, 256, 0, stream>>>(w1, w1b, w2, w2b, n8);
  router_k<<<TTOK / 4, 256, 0, stream>>>(x, se, sidx, rw, rb, e0, e1, tw0, tw1, counts);
  scan_k<<<1, 64, 0, stream>>>(counts, offsets, cursors, tileT, ntiles);
  scatter_k<<<TTOK / 256, 256, 0, stream>>>(e0, e1, tw0, tw1, cursors, buckets, wts, s0, s1);
  gather_k<<<NASSIGN, 256, 0, stream>>>(x, buckets, Xg);

  moe_gemm8_k<DDIM, HDIM, 0><<<1024, 512, 131072, stream>>>(Xg, w1b, b1, tileT, ntiles, Hb, Yr);
  moe_gemm8_k<HDIM, DDIM, 1><<<1024, 512, 131072, stream>>>(Hb, w2b, b2, tileT, ntiles, Hb, Yr);
  combine_k<<<TTOK, 256, 0, stream>>>(Yr, s0, s1, wts, out);
}

// Round 2
// 995.680 us; speedup vs baseline: 1.0389x; 1.0389x over previous
//
#include <hip/hip_runtime.h>
#include <math.h>

#define TTOK 8192
#define DDIM 1024
#define HDIM 4096
#define NEXP 8
#define NASSIGN (TTOK * 2)

typedef float f32x4 __attribute__((ext_vector_type(4)));
typedef short s16x8 __attribute__((ext_vector_type(8)));

__device__ __forceinline__ unsigned short f2bf(float f) {
  union { float f; unsigned int u; } v; v.f = f;
  unsigned int u = v.u;
  u += 0x7FFFu + ((u >> 16) & 1u);   // RNE
  return (unsigned short)(u >> 16);
}

// gelu_tanh(x) = 0.5x(1+tanh(u)) = x * sigmoid(2u),  u = sqrt(2/pi)(x+0.044715x^3)
__device__ __forceinline__ float gelu_fast(float x) {
  float u = 0.7978845608028654f * x * (1.0f + 0.044715f * x * x);
  return x / (1.0f + __expf(-2.0f * u));
}

// ---- fp32 -> bf16 conversion of BOTH weight tensors, coalesced: 1 float4/thread ----
__global__ void cvt_bf16_k(const float* __restrict__ w1, unsigned short* __restrict__ w1b,
                           const float* __restrict__ w2, unsigned short* __restrict__ w2b,
                           int n4) {  // n4 = float4-chunks per tensor
  int i = blockIdx.x * blockDim.x + threadIdx.x;
  const float* src; unsigned short* dst;
  if (i < n4) { src = w1; dst = w1b; } else { src = w2; dst = w2b; i -= n4; }
  float4 v = ((const float4*)src)[i];
  ushort4 o;
  o.x = f2bf(v.x); o.y = f2bf(v.y); o.z = f2bf(v.z); o.w = f2bf(v.w);
  ((ushort4*)dst)[i] = o;
}

// ---- router: logits = (x + se[sidx]) @ rw^T + rb ; top-2 + softmax ----
__global__ void router_k(const float* __restrict__ x, const float* __restrict__ se,
                         const int* __restrict__ sidx, const float* __restrict__ rw,
                         const float* __restrict__ rb,
                         int* __restrict__ e0, int* __restrict__ e1,
                         float* __restrict__ w0, float* __restrict__ w1,
                         int* __restrict__ counts) {
  int t = blockIdx.x * 4 + (threadIdx.x >> 6);
  int lane = threadIdx.x & 63;
  const float4* xp = (const float4*)(x + (size_t)t * DDIM) + lane * 4;
  const float4* sp = (const float4*)(se + (size_t)sidx[0] * DDIM) + lane * 4;
  float xs[16];
#pragma unroll
  for (int c = 0; c < 4; ++c) {
    float4 a = xp[c], b = sp[c];
    xs[c * 4 + 0] = a.x + b.x; xs[c * 4 + 1] = a.y + b.y;
    xs[c * 4 + 2] = a.z + b.z; xs[c * 4 + 3] = a.w + b.w;
  }
  double acc[NEXP];
#pragma unroll
  for (int e = 0; e < NEXP; ++e) acc[e] = 0.0;
#pragma unroll
  for (int e = 0; e < NEXP; ++e) {
    const float4* wp = (const float4*)(rw + (size_t)e * DDIM) + lane * 4;
#pragma unroll
    for (int c = 0; c < 4; ++c) {
      float4 wv = wp[c];
      acc[e] += (double)xs[c * 4 + 0] * wv.x + (double)xs[c * 4 + 1] * wv.y +
                (double)xs[c * 4 + 2] * wv.z + (double)xs[c * 4 + 3] * wv.w;
    }
  }
#pragma unroll
  for (int e = 0; e < NEXP; ++e) {
#pragma unroll
    for (int m = 32; m >= 1; m >>= 1) acc[e] += __shfl_xor(acc[e], m, 64);
  }
  if (lane == 0) {
    float lg[NEXP];
    for (int e = 0; e < NEXP; ++e) lg[e] = (float)acc[e] + rb[e];
    int i0 = 0; float l0 = lg[0];
    for (int e = 1; e < NEXP; ++e) if (lg[e] > l0) { l0 = lg[e]; i0 = e; }
    int i1 = -1; float l1 = -1e30f;
    for (int e = 0; e < NEXP; ++e) if (e != i0 && lg[e] > l1) { l1 = lg[e]; i1 = e; }
    float z = expf(l1 - l0);
    float p0 = 1.0f / (1.0f + z);
    e0[t] = i0; e1[t] = i1; w0[t] = p0; w1[t] = 1.0f - p0;
    atomicAdd(&counts[i0], 1);
    atomicAdd(&counts[i1], 1);
  }
}

// prefix-scan + build m-tile table (256-row tiles: <=80 entries of {m0, row1, e, 0})
__global__ void scan_k(const int* __restrict__ counts, int* __restrict__ offsets,
                       int* __restrict__ cursors, int4* __restrict__ tileT,
                       int* __restrict__ ntiles) {
  if (threadIdx.x == 0 && blockIdx.x == 0) {
    int s = 0;
    for (int e = 0; e < NEXP; ++e) { offsets[e] = s; cursors[e] = s; s += counts[e]; }
    offsets[NEXP] = s;
    int nt = 0;
    for (int e = 0; e < NEXP; ++e)
      for (int m0 = offsets[e]; m0 < offsets[e + 1]; m0 += 256)
        tileT[nt++] = make_int4(m0, offsets[e + 1], e, 0);
    ntiles[0] = nt;
  }
}

__global__ void scatter_k(const int* __restrict__ e0, const int* __restrict__ e1,
                          const float* __restrict__ w0, const float* __restrict__ w1,
                          int* __restrict__ cursors, int* __restrict__ buckets,
                          float* __restrict__ wts, int* __restrict__ s0,
                          int* __restrict__ s1) {
  int t = blockIdx.x * blockDim.x + threadIdx.x;
  if (t >= TTOK) return;
  int a = e0[t];
  int p = atomicAdd(&cursors[a], 1);
  buckets[p] = t; wts[p] = w0[t]; s0[t] = p;
  a = e1[t];
  p = atomicAdd(&cursors[a], 1);
  buckets[p] = t; wts[p] = w1[t]; s1[t] = p;
}

// gather token rows (raw x) into compacted bf16 A matrix
__global__ void gather_k(const float* __restrict__ x, const int* __restrict__ buckets,
                         unsigned short* __restrict__ Xg) {
  int r = blockIdx.x;
  int t = buckets[r];
  int i = threadIdx.x;
  float4 v = ((const float4*)(x + (size_t)t * DDIM))[i];
  ushort4 o;
  o.x = f2bf(v.x); o.y = f2bf(v.y); o.z = f2bf(v.z); o.w = f2bf(v.w);
  ((ushort4*)(Xg + (size_t)r * DDIM))[i] = o;
}

// =====================================================================
// persistent grouped NT GEMM, 256x256 tile, BK=64, 8-phase schedule
// (m201 template). 512 threads = 8 waves (2M x 4N), per-wave 128x64,
// acc[8][4]. LDS 128 KiB dynamic (1 block/CU). Grid = 256 (persistent,
// 1/CU) -- eliminates multi-round block restarts.
// KSP: K-split factor (fc2 uses 2 -> 544 tiles instead of 272, fixing
// the 1.06-tiles/CU makespan quantization; partial sums go to Ya/Yb,
// summed in combine_k). Geometry/sync structure identical for all
// instantiations; only KTILE/NKT and the k-offset change.
// =====================================================================

#define ASP1(p) (const __attribute__((address_space(1))) void*)(p)
#define ASP3(p) (__attribute__((address_space(3))) void*)(p)

#define STAGE_A(KT, H) do {                                                   \
    int kk_ = (KT); if (kk_ >= NKT) kk_ = NKT - 1;                            \
    const int k0_ = kk_ * 64;                                                 \
    unsigned short* d_ = (((KT) & 1) ? LA1 : LA0) + ((H) * 128 + w * 8) * 64; \
    __builtin_amdgcn_global_load_lds(ASP1(aptr[(H) * 2 + 0] + k0_), ASP3(d_), 16, 0, 0);        \
    __builtin_amdgcn_global_load_lds(ASP1(aptr[(H) * 2 + 1] + k0_), ASP3(d_ + 4096), 16, 0, 0); \
  } while (0)

#define STAGE_B(KT, H) do {                                                   \
    int kk_ = (KT); if (kk_ >= NKT) kk_ = NKT - 1;                            \
    const int k0_ = kk_ * 64;                                                 \
    unsigned short* d_ = (((KT) & 1) ? LB1 : LB0) + ((H) * 128 + w * 8) * 64; \
    __builtin_amdgcn_global_load_lds(ASP1(bptr[(H) * 2 + 0] + k0_), ASP3(d_), 16, 0, 0);        \
    __builtin_amdgcn_global_load_lds(ASP1(bptr[(H) * 2 + 1] + k0_), ASP3(d_ + 4096), 16, 0, 0); \
  } while (0)

// one phase: ds_read subtile || stage issue -> barrier -> lgkm(0) -> 16 MFMA
#define PH(SL, QD, RB, STG) do {                                              \
    if (RB) {                                                                 \
      _Pragma("unroll") for (int nj_ = 0; nj_ < 4; ++nj_)                     \
      _Pragma("unroll") for (int ks_ = 0; ks_ < 2; ++ks_)                     \
        bfrag[nj_][ks_] = *(const s16x8*)(((SL) ? LB1 : LB0) +                \
            (wn * 64 + nj_ * 16 + c16) * 64 + (((ks_ * 4 + q) ^ cx) * 8));    \
    }                                                                         \
    s16x8 afr_[2][2];                                                         \
    _Pragma("unroll") for (int m2_ = 0; m2_ < 2; ++m2_)                       \
    _Pragma("unroll") for (int ks_ = 0; ks_ < 2; ++ks_)                       \
      afr_[m2_][ks_] = *(const s16x8*)(((SL) ? LA1 : LA0) +                   \
          (wm * 128 + ((QD) * 2 + m2_) * 16 + c16) * 64 +                     \
          (((ks_ * 4 + q) ^ cx) * 8));                                        \
    STG;                                                                      \
    asm volatile("s_barrier" ::: "memory");                                   \
    asm volatile("s_waitcnt lgkmcnt(0)" ::: "memory");                        \
    __builtin_amdgcn_sched_barrier(0);                                        \
    __builtin_amdgcn_s_setprio(1);                                            \
    _Pragma("unroll") for (int m2_ = 0; m2_ < 2; ++m2_)                       \
    _Pragma("unroll") for (int nj_ = 0; nj_ < 4; ++nj_)                       \
    _Pragma("unroll") for (int ks_ = 0; ks_ < 2; ++ks_)                       \
      acc[(QD) * 2 + m2_][nj_] = __builtin_amdgcn_mfma_f32_16x16x32_bf16(     \
          afr_[m2_][ks_], bfrag[nj_][ks_], acc[(QD) * 2 + m2_][nj_], 0, 0, 0);\
    __builtin_amdgcn_s_setprio(0);                                            \
  } while (0)

#define BARS asm volatile("s_barrier" ::: "memory")
#define VM4  asm volatile("s_waitcnt vmcnt(4)" ::: "memory")

template <int KD, int ND, int EPI, int KSP>
__global__ __launch_bounds__(512, 2) void moe_gemm8_k(
    const unsigned short* __restrict__ A,   // compacted slots x KD (bf16)
    const unsigned short* __restrict__ W,   // NEXP x ND x KD (bf16)
    const float* __restrict__ bias,         // NEXP x ND
    const int4* __restrict__ tileT, const int* __restrict__ ntiles,
    unsigned short* __restrict__ Hout, float* __restrict__ Ya,
    float* __restrict__ Yb) {
  constexpr int NTN = ND / 256;
  constexpr int KTILE = KD / KSP;   // K-range per tile pass
  constexpr int NKT = KTILE / 64;   // K-steps per tile (16 / 32 / 64)
  extern __shared__ unsigned short lds[];
  unsigned short* const LA0 = lds;                 // A slot0: 256x64
  unsigned short* const LA1 = lds + 16384;         // A slot1
  unsigned short* const LB0 = lds + 32768;         // B slot0
  unsigned short* const LB1 = lds + 49152;         // B slot1

  const int tid = threadIdx.x;
  const int lane = tid & 63;
  const int w = tid >> 6;        // wave 0..7
  const int wm = w >> 2;         // 0..1 (M)
  const int wn = w & 3;          // 0..3 (N)
  const int q = lane >> 4;
  const int c16 = lane & 15;
  const int cx = lane & 7;
  const int l8 = lane >> 3;
  const int swz = cx ^ l8;       // pre-swizzled global chunk

  const int ntm = ntiles[0];
  const int total = ntm * NTN * KSP;
  const int xcd = blockIdx.x & 7;
  const int lid = blockIdx.x >> 3;               // 0..31 within XCD
  // contiguous idx-chunk per XCD, m-fastest enumeration -> B panel stays in L2
  const int per = (total + 7) >> 3;
  int begin = xcd * per;
  int end = begin + per; if (end > total) end = total;

  for (int idx = begin + lid; idx < end; idx += 32) {
    const int nbks = idx / ntm;
    const int mt = idx - nbks * ntm;
    const int nb = nbks % NTN;
    const int ks = nbks / NTN;                   // K-split index (0..KSP-1)
    const int koff = ks * KTILE;
    const int4 tl = tileT[mt];
    const int m0 = tl.x, row1 = tl.y, e = tl.z;
    const int n0 = nb * 256;
    const unsigned short* We = W + (size_t)e * ND * KD;

    // staging row base pointers (4 loads each for A and B, 64 rows per load)
    const unsigned short* aptr[4];
    const unsigned short* bptr[4];
#pragma unroll
    for (int i = 0; i < 4; ++i) {
      int ar = m0 + i * 64 + w * 8 + l8;
      if (ar > row1 - 1) ar = row1 - 1;  // clamp: duplicate rows masked at store
      aptr[i] = A + (size_t)ar * KD + koff + swz * 8;
      bptr[i] = We + (size_t)(n0 + i * 64 + w * 8 + l8) * KD + koff + swz * 8;
    }

    f32x4 acc[8][4];
#pragma unroll
    for (int i = 0; i < 8; ++i)
#pragma unroll
      for (int j = 0; j < 4; ++j) acc[i][j] = {0.f, 0.f, 0.f, 0.f};

    s16x8 bfrag[4][2];

    // drain leftover tail-stages + epilogue stores (they complete during the
    // previous tile's epilogue, so this is cheap in steady state)
    asm volatile("s_waitcnt vmcnt(0)" ::: "memory");
    // prologue: A(0), B(0), B(1); A(1) is staged by iter0 ph1-2
    STAGE_A(0, 0); STAGE_A(0, 1);
    STAGE_B(0, 0); STAGE_B(0, 1);
    STAGE_B(1, 0); STAGE_B(1, 1);
    asm volatile("s_waitcnt vmcnt(4)" ::: "memory");  // A(0),B(0) landed
    asm volatile("s_barrier" ::: "memory");

    for (int it = 0; it < NKT / 2; ++it) {
      const int t2 = 2 * it;
      PH(0, 0, 1, STAGE_A(t2 + 1, 0)); BARS;
      PH(0, 1, 0, STAGE_A(t2 + 1, 1)); BARS;
      PH(0, 2, 0, STAGE_B(t2 + 2, 0)); BARS;
      PH(0, 3, 0, STAGE_B(t2 + 2, 1)); VM4; BARS;
      PH(1, 0, 1, STAGE_A(t2 + 2, 0)); BARS;
      PH(1, 1, 0, STAGE_A(t2 + 2, 1)); BARS;
      PH(1, 2, 0, STAGE_B(t2 + 3, 0)); BARS;
      PH(1, 3, 0, STAGE_B(t2 + 3, 1)); VM4; BARS;
    }

    // epilogue: C/D layout col=lane&15, row=(lane>>4)*4+reg  [m89/m91-verified]
    float* const Yp = (KSP > 1 && ks != 0) ? Yb : Ya;
    float bj[4];
#pragma unroll
    for (int nj = 0; nj < 4; ++nj) {
      bj[nj] = bias[(size_t)e * ND + n0 + wn * 64 + nj * 16 + c16];
      if (KSP > 1 && ks != 0) bj[nj] = 0.f;   // bias only once across K-splits
    }
#pragma unroll
    for (int mi = 0; mi < 8; ++mi) {
#pragma unroll
      for (int r = 0; r < 4; ++r) {
        const int m = m0 + wm * 128 + mi * 16 + q * 4 + r;
        if (m < row1) {
#pragma unroll
          for (int nj = 0; nj < 4; ++nj) {
            const int n = n0 + wn * 64 + nj * 16 + c16;
            if (EPI == 0)
              Hout[(size_t)m * ND + n] = f2bf(gelu_fast(acc[mi][nj][r] + bj[nj]));
            else
              Yp[(size_t)m * ND + n] = acc[mi][nj][r] + bj[nj];
          }
        }
      }
    }
  }
}

// out[t] = w(s0)*(Ya+Yb)[s0] + w(s1)*(Ya+Yb)[s1]   (Yb == nullptr -> single Y)
__global__ void combine_k(const float* __restrict__ Ya, const float* __restrict__ Yb,
                          const int* __restrict__ s0, const int* __restrict__ s1,
                          const float* __restrict__ wts, float* __restrict__ out) {
  int t = blockIdx.x;
  int i = threadIdx.x;
  int a = s0[t], b = s1[t];
  float wa = wts[a], wb = wts[b];
  float4 va = ((const float4*)(Ya + (size_t)a * DDIM))[i];
  float4 vb = ((const float4*)(Ya + (size_t)b * DDIM))[i];
  float4 o;
  o.x = wa * va.x + wb * vb.x;
  o.y = wa * va.y + wb * vb.y;
  o.z = wa * va.z + wb * vb.z;
  o.w = wa * va.w + wb * vb.w;
  if (Yb != nullptr) {
    float4 ua = ((const float4*)(Yb + (size_t)a * DDIM))[i];
    float4 ub = ((const float4*)(Yb + (size_t)b * DDIM))[i];
    o.x += wa * ua.x + wb * ub.x;
    o.y += wa * ua.y + wb * ub.y;
    o.z += wa * ua.z + wb * ub.z;
    o.w += wa * ua.w + wb * ub.w;
  }
  ((float4*)(out + (size_t)t * DDIM))[i] = o;
}

extern "C" void kernel_launch(void* const* d_in, const int* in_sizes, int n_in,
                              void* d_out, int out_size, void* d_ws, size_t ws_size,
                              hipStream_t stream) {
  const float* x  = (const float*)d_in[0];
  const float* se = (const float*)d_in[1];
  const float* rw = (const float*)d_in[2];
  const float* rb = (const float*)d_in[3];
  const float* w1 = (const float*)d_in[4];
  const float* b1 = (const float*)d_in[5];
  const float* w2 = (const float*)d_in[6];
  const float* b2 = (const float*)d_in[7];
  const int* sidx = (const int*)d_in[8];
  float* out = (float*)d_out;

  char* ws = (char*)d_ws;
  size_t off = 0;
  unsigned short* w1b = (unsigned short*)(ws + off); off += (size_t)NEXP * HDIM * DDIM * 2;  // 64 MiB
  unsigned short* w2b = (unsigned short*)(ws + off); off += (size_t)NEXP * DDIM * HDIM * 2;  // 64 MiB
  unsigned short* Xg  = (unsigned short*)(ws + off); off += (size_t)NASSIGN * DDIM * 2;      // 32 MiB
  unsigned short* Hb  = (unsigned short*)(ws + off); off += (size_t)NASSIGN * HDIM * 2;      // 128 MiB
  float* Yr = (float*)w1b;  // 64 MiB, overlays w1b (dead after fc1)
  int*   counts  = (int*)(ws + off); off += 64;
  int*   offsets = (int*)(ws + off); off += 64;
  int*   cursors = (int*)(ws + off); off += 64;
  int*   ntiles  = (int*)(ws + off); off += 64;
  int*   e0  = (int*)(ws + off);   off += (size_t)TTOK * 4;
  int*   e1  = (int*)(ws + off);   off += (size_t)TTOK * 4;
  float* tw0 = (float*)(ws + off); off += (size_t)TTOK * 4;
  float* tw1 = (float*)(ws + off); off += (size_t)TTOK * 4;
  int*   s0  = (int*)(ws + off);   off += (size_t)TTOK * 4;
  int*   s1  = (int*)(ws + off);   off += (size_t)TTOK * 4;
  int*   buckets = (int*)(ws + off); off += (size_t)NASSIGN * 4;
  float* wts = (float*)(ws + off);   off += (size_t)NASSIGN * 4;
  int4*  tileT = (int4*)(ws + off);  off += 256 * 16;

  // K-split partial buffer for fc2 (only if workspace allows)
  size_t yb_bytes = (size_t)NASSIGN * DDIM * 4;  // 64 MiB
  float* Yb = nullptr;
  if (ws_size >= off + yb_bytes) { Yb = (float*)(ws + off); off += yb_bytes; }

  // 128 KiB dynamic LDS opt-in (host-side attribute, graph-capture safe)
  static int lds_attr_done = 0;
  if (!lds_attr_done) {
    (void)hipFuncSetAttribute((const void*)moe_gemm8_k<DDIM, HDIM, 0, 1>,
                              hipFuncAttributeMaxDynamicSharedMemorySize, 131072);
    (void)hipFuncSetAttribute((const void*)moe_gemm8_k<HDIM, DDIM, 1, 2>,
                              hipFuncAttributeMaxDynamicSharedMemorySize, 131072);
    (void)hipFuncSetAttribute((const void*)moe_gemm8_k<HDIM, DDIM, 1, 1>,
                              hipFuncAttributeMaxDynamicSharedMemorySize, 131072);
    lds_attr_done = 1;
  }

  hipMemsetAsync(counts, 0, 64, stream);

  const int n4 = NEXP * HDIM * DDIM / 4;
  cvt_bf16_k<<<2 * n4 / 256, 256, 0, stream>>>(w1, w1b, w2, w2b, n4);
  router_k<<<TTOK / 4, 256, 0, stream>>>(x, se, sidx, rw, rb, e0, e1, tw0, tw1, counts);
  scan_k<<<1, 64, 0, stream>>>(counts, offsets, cursors, tileT, ntiles);
  scatter_k<<<TTOK / 256, 256, 0, stream>>>(e0, e1, tw0, tw1, cursors, buckets, wts, s0, s1);
  gather_k<<<NASSIGN, 256, 0, stream>>>(x, buckets, Xg);

  moe_gemm8_k<DDIM, HDIM, 0, 1><<<256, 512, 131072, stream>>>(
      Xg, w1b, b1, tileT, ntiles, Hb, Yr, nullptr);
  if (Yb != nullptr)
    moe_gemm8_k<HDIM, DDIM, 1, 2><<<256, 512, 131072, stream>>>(
        Hb, w2b, b2, tileT, ntiles, Hb, Yr, Yb);
  else
    moe_gemm8_k<HDIM, DDIM, 1, 1><<<256, 512, 131072, stream>>>(
        Hb, w2b, b2, tileT, ntiles, Hb, Yr, nullptr);
  combine_k<<<TTOK, 256, 0, stream>>>(Yr, Yb, s0, s1, wts, out);
}

// Round 3
// 990.840 us; speedup vs baseline: 1.0440x; 1.0049x over previous
//
#include <hip/hip_runtime.h>
#include <math.h>

#define TTOK 8192
#define DDIM 1024
#define HDIM 4096
#define NEXP 8
#define NASSIGN (TTOK * 2)

typedef float f32x4 __attribute__((ext_vector_type(4)));
typedef short s16x8 __attribute__((ext_vector_type(8)));

__device__ __forceinline__ unsigned short f2bf(float f) {
  union { float f; unsigned int u; } v; v.f = f;
  unsigned int u = v.u;
  u += 0x7FFFu + ((u >> 16) & 1u);   // RNE
  return (unsigned short)(u >> 16);
}

// gelu_tanh(x) = 0.5x(1+tanh(u)) = x * sigmoid(2u),  u = sqrt(2/pi)(x+0.044715x^3)
__device__ __forceinline__ float gelu_fast(float x) {
  float u = 0.7978845608028654f * x * (1.0f + 0.044715f * x * x);
  return x / (1.0f + __expf(-2.0f * u));
}

// ---- fp32 -> bf16 conversion of BOTH weight tensors, coalesced: 1 float4/thread ----
__global__ void cvt_bf16_k(const float* __restrict__ w1, unsigned short* __restrict__ w1b,
                           const float* __restrict__ w2, unsigned short* __restrict__ w2b,
                           int n4) {  // n4 = float4-chunks per tensor
  int i = blockIdx.x * blockDim.x + threadIdx.x;
  const float* src; unsigned short* dst;
  if (i < n4) { src = w1; dst = w1b; } else { src = w2; dst = w2b; i -= n4; }
  float4 v = ((const float4*)src)[i];
  ushort4 o;
  o.x = f2bf(v.x); o.y = f2bf(v.y); o.z = f2bf(v.z); o.w = f2bf(v.w);
  ((ushort4*)dst)[i] = o;
}

// ---- router: logits = (x + se[sidx]) @ rw^T + rb ; top-2 + softmax ----
__global__ void router_k(const float* __restrict__ x, const float* __restrict__ se,
                         const int* __restrict__ sidx, const float* __restrict__ rw,
                         const float* __restrict__ rb,
                         int* __restrict__ e0, int* __restrict__ e1,
                         float* __restrict__ w0, float* __restrict__ w1,
                         int* __restrict__ counts) {
  int t = blockIdx.x * 4 + (threadIdx.x >> 6);
  int lane = threadIdx.x & 63;
  const float4* xp = (const float4*)(x + (size_t)t * DDIM) + lane * 4;
  const float4* sp = (const float4*)(se + (size_t)sidx[0] * DDIM) + lane * 4;
  float xs[16];
#pragma unroll
  for (int c = 0; c < 4; ++c) {
    float4 a = xp[c], b = sp[c];
    xs[c * 4 + 0] = a.x + b.x; xs[c * 4 + 1] = a.y + b.y;
    xs[c * 4 + 2] = a.z + b.z; xs[c * 4 + 3] = a.w + b.w;
  }
  double acc[NEXP];
#pragma unroll
  for (int e = 0; e < NEXP; ++e) acc[e] = 0.0;
#pragma unroll
  for (int e = 0; e < NEXP; ++e) {
    const float4* wp = (const float4*)(rw + (size_t)e * DDIM) + lane * 4;
#pragma unroll
    for (int c = 0; c < 4; ++c) {
      float4 wv = wp[c];
      acc[e] += (double)xs[c * 4 + 0] * wv.x + (double)xs[c * 4 + 1] * wv.y +
                (double)xs[c * 4 + 2] * wv.z + (double)xs[c * 4 + 3] * wv.w;
    }
  }
#pragma unroll
  for (int e = 0; e < NEXP; ++e) {
#pragma unroll
    for (int m = 32; m >= 1; m >>= 1) acc[e] += __shfl_xor(acc[e], m, 64);
  }
  if (lane == 0) {
    float lg[NEXP];
    for (int e = 0; e < NEXP; ++e) lg[e] = (float)acc[e] + rb[e];
    int i0 = 0; float l0 = lg[0];
    for (int e = 1; e < NEXP; ++e) if (lg[e] > l0) { l0 = lg[e]; i0 = e; }
    int i1 = -1; float l1 = -1e30f;
    for (int e = 0; e < NEXP; ++e) if (e != i0 && lg[e] > l1) { l1 = lg[e]; i1 = e; }
    float z = expf(l1 - l0);
    float p0 = 1.0f / (1.0f + z);
    e0[t] = i0; e1[t] = i1; w0[t] = p0; w1[t] = 1.0f - p0;
    atomicAdd(&counts[i0], 1);
    atomicAdd(&counts[i1], 1);
  }
}

// prefix-scan + build m-tile table (256-row tiles: <=80 entries of {m0, row1, e, 0})
__global__ void scan_k(const int* __restrict__ counts, int* __restrict__ offsets,
                       int* __restrict__ cursors, int4* __restrict__ tileT,
                       int* __restrict__ ntiles) {
  if (threadIdx.x == 0 && blockIdx.x == 0) {
    int s = 0;
    for (int e = 0; e < NEXP; ++e) { offsets[e] = s; cursors[e] = s; s += counts[e]; }
    offsets[NEXP] = s;
    int nt = 0;
    for (int e = 0; e < NEXP; ++e)
      for (int m0 = offsets[e]; m0 < offsets[e + 1]; m0 += 256)
        tileT[nt++] = make_int4(m0, offsets[e + 1], e, 0);
    ntiles[0] = nt;
  }
}

__global__ void scatter_k(const int* __restrict__ e0, const int* __restrict__ e1,
                          const float* __restrict__ w0, const float* __restrict__ w1,
                          int* __restrict__ cursors, int* __restrict__ buckets,
                          float* __restrict__ wts, int* __restrict__ s0,
                          int* __restrict__ s1) {
  int t = blockIdx.x * blockDim.x + threadIdx.x;
  if (t >= TTOK) return;
  int a = e0[t];
  int p = atomicAdd(&cursors[a], 1);
  buckets[p] = t; wts[p] = w0[t]; s0[t] = p;
  a = e1[t];
  p = atomicAdd(&cursors[a], 1);
  buckets[p] = t; wts[p] = w1[t]; s1[t] = p;
}

// gather token rows (raw x) into compacted bf16 A matrix
__global__ void gather_k(const float* __restrict__ x, const int* __restrict__ buckets,
                         unsigned short* __restrict__ Xg) {
  int r = blockIdx.x;
  int t = buckets[r];
  int i = threadIdx.x;
  float4 v = ((const float4*)(x + (size_t)t * DDIM))[i];
  ushort4 o;
  o.x = f2bf(v.x); o.y = f2bf(v.y); o.z = f2bf(v.z); o.w = f2bf(v.w);
  ((ushort4*)(Xg + (size_t)r * DDIM))[i] = o;
}

// =====================================================================
// persistent grouped NT GEMM, 256x256 tile, BK=64, 8-phase schedule.
// CRITICAL vs R2: barriers are __builtin_amdgcn_s_barrier() and waitcnt
// asm has NO "memory" clobber -- an asm memory clobber makes the backend
// insert s_waitcnt vmcnt(0) before it, silently degrading the counted-
// vmcnt pipeline to drain-per-phase (m218 V1 ~ the 27% MfmaUtil we saw).
// sched_barrier(0) after each wait pins MFMA/ds_read motion (rule #18).
// Enumeration is n-fastest within each XCD chunk: A-panel stays in L2,
// B re-reads come from LLC.
// =====================================================================

#define ASP1(p) (const __attribute__((address_space(1))) void*)(p)
#define ASP3(p) (__attribute__((address_space(3))) void*)(p)

#define STAGE_A(KT, H) do {                                                   \
    int kk_ = (KT); if (kk_ >= NKT) kk_ = NKT - 1;                            \
    const int k0_ = kk_ * 64;                                                 \
    unsigned short* d_ = (((KT) & 1) ? LA1 : LA0) + ((H) * 128 + w * 8) * 64; \
    __builtin_amdgcn_global_load_lds(ASP1(aptr[(H) * 2 + 0] + k0_), ASP3(d_), 16, 0, 0);        \
    __builtin_amdgcn_global_load_lds(ASP1(aptr[(H) * 2 + 1] + k0_), ASP3(d_ + 4096), 16, 0, 0); \
  } while (0)

#define STAGE_B(KT, H) do {                                                   \
    int kk_ = (KT); if (kk_ >= NKT) kk_ = NKT - 1;                            \
    const int k0_ = kk_ * 64;                                                 \
    unsigned short* d_ = (((KT) & 1) ? LB1 : LB0) + ((H) * 128 + w * 8) * 64; \
    __builtin_amdgcn_global_load_lds(ASP1(bptr[(H) * 2 + 0] + k0_), ASP3(d_), 16, 0, 0);        \
    __builtin_amdgcn_global_load_lds(ASP1(bptr[(H) * 2 + 1] + k0_), ASP3(d_ + 4096), 16, 0, 0); \
  } while (0)

// one phase: ds_read subtile || stage issue -> barrier -> lgkm(0) -> 16 MFMA
#define PH(SL, QD, RB, STG) do {                                              \
    if (RB) {                                                                 \
      _Pragma("unroll") for (int nj_ = 0; nj_ < 4; ++nj_)                     \
      _Pragma("unroll") for (int ks_ = 0; ks_ < 2; ++ks_)                     \
        bfrag[nj_][ks_] = *(const s16x8*)(((SL) ? LB1 : LB0) +                \
            (wn * 64 + nj_ * 16 + c16) * 64 + (((ks_ * 4 + q) ^ cx) * 8));    \
    }                                                                         \
    s16x8 afr_[2][2];                                                         \
    _Pragma("unroll") for (int m2_ = 0; m2_ < 2; ++m2_)                       \
    _Pragma("unroll") for (int ks_ = 0; ks_ < 2; ++ks_)                       \
      afr_[m2_][ks_] = *(const s16x8*)(((SL) ? LA1 : LA0) +                   \
          (wm * 128 + ((QD) * 2 + m2_) * 16 + c16) * 64 +                     \
          (((ks_ * 4 + q) ^ cx) * 8));                                        \
    STG;                                                                      \
    __builtin_amdgcn_s_barrier();                                             \
    asm volatile("s_waitcnt lgkmcnt(0)");                                     \
    __builtin_amdgcn_sched_barrier(0);                                        \
    __builtin_amdgcn_s_setprio(1);                                            \
    _Pragma("unroll") for (int m2_ = 0; m2_ < 2; ++m2_)                       \
    _Pragma("unroll") for (int nj_ = 0; nj_ < 4; ++nj_)                       \
    _Pragma("unroll") for (int ks_ = 0; ks_ < 2; ++ks_)                       \
      acc[(QD) * 2 + m2_][nj_] = __builtin_amdgcn_mfma_f32_16x16x32_bf16(     \
          afr_[m2_][ks_], bfrag[nj_][ks_], acc[(QD) * 2 + m2_][nj_], 0, 0, 0);\
    __builtin_amdgcn_s_setprio(0);                                            \
  } while (0)

#define BARS __builtin_amdgcn_s_barrier()
#define VM4 do { asm volatile("s_waitcnt vmcnt(4)");                          \
                 __builtin_amdgcn_sched_barrier(0); } while (0)

template <int KD, int ND, int EPI, int KSP>
__global__ __launch_bounds__(512, 2) void moe_gemm8_k(
    const unsigned short* __restrict__ A,   // compacted slots x KD (bf16)
    const unsigned short* __restrict__ W,   // NEXP x ND x KD (bf16)
    const float* __restrict__ bias,         // NEXP x ND
    const int4* __restrict__ tileT, const int* __restrict__ ntiles,
    unsigned short* __restrict__ Hout, float* __restrict__ Ya,
    float* __restrict__ Yb) {
  constexpr int NTN = ND / 256;
  constexpr int KTILE = KD / KSP;   // K-range per tile pass
  constexpr int NKT = KTILE / 64;   // K-steps per tile
  constexpr int NBK = NTN * KSP;    // n/k combos per m-tile (compile-time)
  extern __shared__ unsigned short lds[];
  unsigned short* const LA0 = lds;                 // A slot0: 256x64
  unsigned short* const LA1 = lds + 16384;         // A slot1
  unsigned short* const LB0 = lds + 32768;         // B slot0
  unsigned short* const LB1 = lds + 49152;         // B slot1

  const int tid = threadIdx.x;
  const int lane = tid & 63;
  const int w = tid >> 6;        // wave 0..7
  const int wm = w >> 2;         // 0..1 (M)
  const int wn = w & 3;          // 0..3 (N)
  const int q = lane >> 4;
  const int c16 = lane & 15;
  const int cx = lane & 7;
  const int l8 = lane >> 3;
  const int swz = cx ^ l8;       // pre-swizzled global chunk

  const int ntm = ntiles[0];
  const int total = ntm * NBK;
  const int xcd = blockIdx.x & 7;
  const int lid = blockIdx.x >> 3;               // 0..31 within XCD
  // contiguous idx-chunk per XCD, n-fastest: A-panel L2-resident, B from LLC
  const int per = (total + 7) >> 3;
  int begin = xcd * per;
  int end = begin + per; if (end > total) end = total;

  for (int idx = begin + lid; idx < end; idx += 32) {
    const int mt = idx / NBK;                    // compile-time divisor
    const int rem = idx - mt * NBK;
    const int nb = rem % NTN;
    const int ks = rem / NTN;                    // K-split index (0..KSP-1)
    const int koff = ks * KTILE;
    const int4 tl = tileT[mt];
    const int m0 = tl.x, row1 = tl.y, e = tl.z;
    const int n0 = nb * 256;
    const unsigned short* We = W + (size_t)e * ND * KD;

    // staging row base pointers (4 loads each for A and B, 64 rows per load)
    const unsigned short* aptr[4];
    const unsigned short* bptr[4];
#pragma unroll
    for (int i = 0; i < 4; ++i) {
      int ar = m0 + i * 64 + w * 8 + l8;
      if (ar > row1 - 1) ar = row1 - 1;  // clamp: duplicate rows masked at store
      aptr[i] = A + (size_t)ar * KD + koff + swz * 8;
      bptr[i] = We + (size_t)(n0 + i * 64 + w * 8 + l8) * KD + koff + swz * 8;
    }

    f32x4 acc[8][4];
#pragma unroll
    for (int i = 0; i < 8; ++i)
#pragma unroll
      for (int j = 0; j < 4; ++j) acc[i][j] = {0.f, 0.f, 0.f, 0.f};

    s16x8 bfrag[4][2];

    // drain prev tile's tail-stages + epilogue stores (same-wave LDS WW hazard)
    asm volatile("s_waitcnt vmcnt(0)");
    __builtin_amdgcn_sched_barrier(0);
    // prologue: A(0), B(0), B(1); A(1) is staged by iter0 ph1-2
    STAGE_A(0, 0); STAGE_A(0, 1);
    STAGE_B(0, 0); STAGE_B(0, 1);
    STAGE_B(1, 0); STAGE_B(1, 1);
    asm volatile("s_waitcnt vmcnt(4)");  // A(0),B(0) landed
    __builtin_amdgcn_sched_barrier(0);
    __builtin_amdgcn_s_barrier();

    for (int it = 0; it < NKT / 2; ++it) {
      const int t2 = 2 * it;
      PH(0, 0, 1, STAGE_A(t2 + 1, 0)); BARS;
      PH(0, 1, 0, STAGE_A(t2 + 1, 1)); BARS;
      PH(0, 2, 0, STAGE_B(t2 + 2, 0)); BARS;
      PH(0, 3, 0, STAGE_B(t2 + 2, 1)); VM4; BARS;
      PH(1, 0, 1, STAGE_A(t2 + 2, 0)); BARS;
      PH(1, 1, 0, STAGE_A(t2 + 2, 1)); BARS;
      PH(1, 2, 0, STAGE_B(t2 + 3, 0)); BARS;
      PH(1, 3, 0, STAGE_B(t2 + 3, 1)); VM4; BARS;
    }

    // epilogue: C/D layout col=lane&15, row=(lane>>4)*4+reg  [m89/m91-verified]
    float* const Yp = (KSP > 1 && ks != 0) ? Yb : Ya;
    float bj[4];
#pragma unroll
    for (int nj = 0; nj < 4; ++nj) {
      bj[nj] = bias[(size_t)e * ND + n0 + wn * 64 + nj * 16 + c16];
      if (KSP > 1 && ks != 0) bj[nj] = 0.f;   // bias only once across K-splits
    }
#pragma unroll
    for (int mi = 0; mi < 8; ++mi) {
#pragma unroll
      for (int r = 0; r < 4; ++r) {
        const int m = m0 + wm * 128 + mi * 16 + q * 4 + r;
        if (m < row1) {
#pragma unroll
          for (int nj = 0; nj < 4; ++nj) {
            const int n = n0 + wn * 64 + nj * 16 + c16;
            if (EPI == 0)
              Hout[(size_t)m * ND + n] = f2bf(gelu_fast(acc[mi][nj][r] + bj[nj]));
            else
              Yp[(size_t)m * ND + n] = acc[mi][nj][r] + bj[nj];
          }
        }
      }
    }
  }
}

// out[t] = w(s0)*(Ya+Yb)[s0] + w(s1)*(Ya+Yb)[s1]   (Yb == nullptr -> single Y)
__global__ void combine_k(const float* __restrict__ Ya, const float* __restrict__ Yb,
                          const int* __restrict__ s0, const int* __restrict__ s1,
                          const float* __restrict__ wts, float* __restrict__ out) {
  int t = blockIdx.x;
  int i = threadIdx.x;
  int a = s0[t], b = s1[t];
  float wa = wts[a], wb = wts[b];
  float4 va = ((const float4*)(Ya + (size_t)a * DDIM))[i];
  float4 vb = ((const float4*)(Ya + (size_t)b * DDIM))[i];
  float4 o;
  o.x = wa * va.x + wb * vb.x;
  o.y = wa * va.y + wb * vb.y;
  o.z = wa * va.z + wb * vb.z;
  o.w = wa * va.w + wb * vb.w;
  if (Yb != nullptr) {
    float4 ua = ((const float4*)(Yb + (size_t)a * DDIM))[i];
    float4 ub = ((const float4*)(Yb + (size_t)b * DDIM))[i];
    o.x += wa * ua.x + wb * ub.x;
    o.y += wa * ua.y + wb * ub.y;
    o.z += wa * ua.z + wb * ub.z;
    o.w += wa * ua.w + wb * ub.w;
  }
  ((float4*)(out + (size_t)t * DDIM))[i] = o;
}

extern "C" void kernel_launch(void* const* d_in, const int* in_sizes, int n_in,
                              void* d_out, int out_size, void* d_ws, size_t ws_size,
                              hipStream_t stream) {
  const float* x  = (const float*)d_in[0];
  const float* se = (const float*)d_in[1];
  const float* rw = (const float*)d_in[2];
  const float* rb = (const float*)d_in[3];
  const float* w1 = (const float*)d_in[4];
  const float* b1 = (const float*)d_in[5];
  const float* w2 = (const float*)d_in[6];
  const float* b2 = (const float*)d_in[7];
  const int* sidx = (const int*)d_in[8];
  float* out = (float*)d_out;

  char* ws = (char*)d_ws;
  size_t off = 0;
  unsigned short* w1b = (unsigned short*)(ws + off); off += (size_t)NEXP * HDIM * DDIM * 2;  // 64 MiB
  unsigned short* w2b = (unsigned short*)(ws + off); off += (size_t)NEXP * DDIM * HDIM * 2;  // 64 MiB
  unsigned short* Xg  = (unsigned short*)(ws + off); off += (size_t)NASSIGN * DDIM * 2;      // 32 MiB
  unsigned short* Hb  = (unsigned short*)(ws + off); off += (size_t)NASSIGN * HDIM * 2;      // 128 MiB
  float* Yr = (float*)w1b;  // 64 MiB, overlays w1b (dead after fc1)
  int*   counts  = (int*)(ws + off); off += 64;
  int*   offsets = (int*)(ws + off); off += 64;
  int*   cursors = (int*)(ws + off); off += 64;
  int*   ntiles  = (int*)(ws + off); off += 64;
  int*   e0  = (int*)(ws + off);   off += (size_t)TTOK * 4;
  int*   e1  = (int*)(ws + off);   off += (size_t)TTOK * 4;
  float* tw0 = (float*)(ws + off); off += (size_t)TTOK * 4;
  float* tw1 = (float*)(ws + off); off += (size_t)TTOK * 4;
  int*   s0  = (int*)(ws + off);   off += (size_t)TTOK * 4;
  int*   s1  = (int*)(ws + off);   off += (size_t)TTOK * 4;
  int*   buckets = (int*)(ws + off); off += (size_t)NASSIGN * 4;
  float* wts = (float*)(ws + off);   off += (size_t)NASSIGN * 4;
  int4*  tileT = (int4*)(ws + off);  off += 256 * 16;

  // K-split partial buffer for fc2 (only if workspace allows)
  size_t yb_bytes = (size_t)NASSIGN * DDIM * 4;  // 64 MiB
  float* Yb = nullptr;
  if (ws_size >= off + yb_bytes) { Yb = (float*)(ws + off); off += yb_bytes; }

  // 128 KiB dynamic LDS opt-in (host-side attribute, graph-capture safe)
  static int lds_attr_done = 0;
  if (!lds_attr_done) {
    (void)hipFuncSetAttribute((const void*)moe_gemm8_k<DDIM, HDIM, 0, 1>,
                              hipFuncAttributeMaxDynamicSharedMemorySize, 131072);
    (void)hipFuncSetAttribute((const void*)moe_gemm8_k<HDIM, DDIM, 1, 2>,
                              hipFuncAttributeMaxDynamicSharedMemorySize, 131072);
    (void)hipFuncSetAttribute((const void*)moe_gemm8_k<HDIM, DDIM, 1, 1>,
                              hipFuncAttributeMaxDynamicSharedMemorySize, 131072);
    lds_attr_done = 1;
  }

  hipMemsetAsync(counts, 0, 64, stream);

  const int n4 = NEXP * HDIM * DDIM / 4;
  cvt_bf16_k<<<2 * n4 / 256, 256, 0, stream>>>(w1, w1b, w2, w2b, n4);
  router_k<<<TTOK / 4, 256, 0, stream>>>(x, se, sidx, rw, rb, e0, e1, tw0, tw1, counts);
  scan_k<<<1, 64, 0, stream>>>(counts, offsets, cursors, tileT, ntiles);
  scatter_k<<<TTOK / 256, 256, 0, stream>>>(e0, e1, tw0, tw1, cursors, buckets, wts, s0, s1);
  gather_k<<<NASSIGN, 256, 0, stream>>>(x, buckets, Xg);

  moe_gemm8_k<DDIM, HDIM, 0, 1><<<256, 512, 131072, stream>>>(
      Xg, w1b, b1, tileT, ntiles, Hb, Yr, nullptr);
  if (Yb != nullptr)
    moe_gemm8_k<HDIM, DDIM, 1, 2><<<256, 512, 131072, stream>>>(
        Hb, w2b, b2, tileT, ntiles, Hb, Yr, Yb);
  else
    moe_gemm8_k<HDIM, DDIM, 1, 1><<<256, 512, 131072, stream>>>(
        Hb, w2b, b2, tileT, ntiles, Hb, Yr, nullptr);
  combine_k<<<TTOK, 256, 0, stream>>>(Yr, Yb, s0, s1, wts, out);
}